// Round 9
// baseline (479.478 us; speedup 1.0000x reference)
//
#include <hip/hip_runtime.h>
#include <hip/hip_fp16.h>

typedef __attribute__((ext_vector_type(8))) __bf16 bf16x8;
typedef _Float16 f16x8 __attribute__((ext_vector_type(8)));
typedef __attribute__((ext_vector_type(4))) float floatx4;

#define NN 16384
#define EPS 1e-5f
// bucket = node >> 4 : 16 nodes/bucket, 1024 buckets per branch
#define NBUK 1024

// prep_misc block-range constants
#define PM_ZB 8
#define PM_O1 (PM_ZB)            // 8    : w3 transpose (96)
#define PM_O2 (PM_O1 + 96)       // 104  : fusw transpose (1728)
#define PM_O3 (PM_O2 + 1728)     // 1832 : convert3 (6144)
#define PM_O4 (PM_O3 + 6144)     // 7976 : convert_sem (4096)
#define PM_O5 (PM_O4 + 4096)     // 12072: prep_pointnet (2)
#define PM_O6 (PM_O5 + 2)        // 12074: fuse_bias (768)
#define PM_TOT (PM_O6 + 768)     // 12842

__device__ __forceinline__ unsigned short f2b(float f) {
  unsigned u = __float_as_uint(f);
  u += 0x7fffu + ((u >> 16) & 1u);
  return (unsigned short)(u >> 16);
}
__device__ __forceinline__ float b2f(unsigned short u) {
  return __uint_as_float(((unsigned)u) << 16);
}

// async global->LDS, 16B per lane; LDS dest must be wave-uniform base
// (lane i lands at base + i*16B).
__device__ __forceinline__ void gl_lds16(const void* g, void* l) {
  __builtin_amdgcn_global_load_lds(
      (const __attribute__((address_space(1))) void*)(unsigned long long)g,
      (__attribute__((address_space(3))) void*)(unsigned long long)l, 16, 0, 0);
}

// kept for harness symbol expectations; never launched
__global__ void RoboNodeEncoder_88424786690347_kernel() {}

// ---------------- mega-prep: 7 independent preprocessing tasks, one launch.
// Tasks are block-disjoint; each block takes exactly one branch.
__global__ __launch_bounds__(256) void prep_misc(
    unsigned* __restrict__ bcnt,
    const float* __restrict__ pw3, const float* __restrict__ aw3,
    unsigned short* __restrict__ w3T,
    const float* __restrict__ fusw, unsigned short* __restrict__ fusT,
    const float* __restrict__ pw4, const float* __restrict__ aw4,
    const float* __restrict__ semw, unsigned short* __restrict__ wB,
    const float* __restrict__ x_sem, unsigned short* __restrict__ semB, int do_sem,
    const float* __restrict__ w1p, const float* __restrict__ b1p,
    const float* __restrict__ g1p, const float* __restrict__ be1p,
    const float* __restrict__ w1a, const float* __restrict__ b1a,
    const float* __restrict__ g1a, const float* __restrict__ be1a,
    const float* __restrict__ w2p, const float* __restrict__ w2a,
    unsigned* __restrict__ Gp2, float* __restrict__ Mq2,
    unsigned short* __restrict__ w2T,
    const float* __restrict__ fusb, const float* __restrict__ pb4,
    const float* __restrict__ ab4, const float* __restrict__ semb,
    float* __restrict__ bias_tot) {
  int blk = blockIdx.x;
  int tid = threadIdx.x;

  if (blk < PM_O1) {
    // ---- task 0: zero bcnt (2*NBUK u32)
    int i = blk * 256 + tid;
    if (i < 2 * NBUK) bcnt[i] = 0u;

  } else if (blk < PM_O2) {
    // ---- task 1: w3 transpose pair (R=64, C=768), 96 blocks
    __shared__ float t[32][33];
    int idx = blk - PM_O1;
    int z = idx / 48, rem = idx % 48, Y = rem / 24, X = rem % 24;
    const float* in = z ? aw3 : pw3;
    unsigned short* out = w3T + (size_t)z * 768 * 64;
    int bx = X * 32, by = Y * 32;
    int x = tid & 31, y = tid >> 5;
#pragma unroll
    for (int i = 0; i < 32; i += 8) t[y + i][x] = in[(size_t)(by + y + i) * 768 + bx + x];
    __syncthreads();
#pragma unroll
    for (int i = 0; i < 32; i += 8) out[(size_t)(bx + y + i) * 64 + by + x] = f2b(t[x][y + i]);

  } else if (blk < PM_O3) {
    // ---- task 2: fusw transpose (R=2304, C=768), 1728 blocks
    __shared__ float t[32][33];
    int idx = blk - PM_O2;
    int X = idx % 24, Y = idx / 24;
    int bx = X * 32, by = Y * 32;
    int x = tid & 31, y = tid >> 5;
#pragma unroll
    for (int i = 0; i < 32; i += 8) t[y + i][x] = fusw[(size_t)(by + y + i) * 768 + bx + x];
    __syncthreads();
#pragma unroll
    for (int i = 0; i < 32; i += 8) fusT[(size_t)(bx + y + i) * 2304 + by + x] = f2b(t[x][y + i]);

  } else if (blk < PM_O4) {
    // ---- task 3: convert3 (pw4|aw4|semw -> bf16 wB), 6144 blocks
    int i = (blk - PM_O3) * 256 + tid;
    float v;
    if (i < 589824) v = pw4[i];
    else if (i < 1179648) v = aw4[i - 589824];
    else v = semw[i - 1179648];
    wB[i] = f2b(v);

  } else if (blk < PM_O5) {
    // ---- task 4: convert_sem (f32 -> bf16, 8/thread), 4096 blocks
    if (!do_sem) return;
    int i = (blk - PM_O4) * 256 + tid;
    const float4* p = reinterpret_cast<const float4*>(x_sem);
    float4 fa = p[2 * i];
    float4 fb = p[2 * i + 1];
    uint4 pk;
    pk.x = (unsigned)f2b(fa.x) | ((unsigned)f2b(fa.y) << 16);
    pk.y = (unsigned)f2b(fa.z) | ((unsigned)f2b(fa.w) << 16);
    pk.z = (unsigned)f2b(fb.x) | ((unsigned)f2b(fb.y) << 16);
    pk.w = (unsigned)f2b(fb.z) | ((unsigned)f2b(fb.w) << 16);
    reinterpret_cast<uint4*>(semB)[i] = pk;

  } else if (blk < PM_O6) {
    // ---- task 5: prep_pointnet (folded-LN consts, f16 packs), 2 blocks
    if (tid >= 64) return;
    int br = blk - PM_O5;
    const float* w1 = br ? w1a : w1p;
    const float* b1 = br ? b1a : b1p;
    const float* g1 = br ? g1a : g1p;
    const float* be1 = br ? be1a : be1p;
    const float* w2 = br ? w2a : w2p;
    unsigned* Gp = Gp2 + br * 160;
    float* Mq = Mq2 + br * 16;
    unsigned short* w2t = w2T + br * 4096;
    int k = tid;
#pragma unroll
    for (int n = 0; n < 64; n++)
      w2t[n * 64 + k] = __half_as_ushort(__float2half(w2[k * 64 + n]));
    float c[4] = {w1[k], w1[64 + k], w1[128 + k], b1[k]};
#pragma unroll
    for (int a = 0; a < 4; a++) {
      float s = c[a];
#pragma unroll
      for (int off = 32; off > 0; off >>= 1) s += __shfl_xor(s, off, 64);
      c[a] -= s * (1.f / 64.f);
    }
    float g = g1[k];
#pragma unroll
    for (int a = 0; a < 4; a++) {
      float Ga = c[a] * g;
      float Gb = __shfl_down(Ga, 1, 64);
      if (!(k & 1))
        Gp[a * 32 + (k >> 1)] =
            (unsigned)__half_as_ushort(__float2half(Ga)) |
            ((unsigned)__half_as_ushort(__float2half(Gb)) << 16);
    }
    {
      float Ba = be1[k];
      float Bb = __shfl_down(Ba, 1, 64);
      if (!(k & 1))
        Gp[128 + (k >> 1)] =
            (unsigned)__half_as_ushort(__float2half(Ba)) |
            ((unsigned)__half_as_ushort(__float2half(Bb)) << 16);
    }
    const int AA[10] = {0, 1, 2, 3, 0, 0, 0, 1, 1, 2};
    const int BB[10] = {0, 1, 2, 3, 1, 2, 3, 2, 3, 3};
#pragma unroll
    for (int t = 0; t < 10; t++) {
      float s = c[AA[t]] * c[BB[t]];
#pragma unroll
      for (int off = 32; off > 0; off >>= 1) s += __shfl_xor(s, off, 64);
      s *= (1.f / 64.f);
      if (t >= 4) s *= 2.f;
      if (k == 0) Mq[t] = s;
    }

  } else {
    // ---- task 6: fuse_bias (fold upstream biases), 768 blocks
    __shared__ float sm[4];
    int c = blk - PM_O6;
    float s = 0.f;
    for (int j = tid; j < 768; j += 256) {
      s = fmaf(pb4[j],  fusw[(size_t)j * 768 + c], s);
      s = fmaf(ab4[j],  fusw[(size_t)(768 + j) * 768 + c], s);
      s = fmaf(semb[j], fusw[(size_t)(1536 + j) * 768 + c], s);
    }
#pragma unroll
    for (int off = 32; off > 0; off >>= 1) s += __shfl_xor(s, off, 64);
    if ((tid & 63) == 0) sm[tid >> 6] = s;
    __syncthreads();
    if (tid == 0) bias_tot[c] = sm[0] + sm[1] + sm[2] + sm[3] + fusb[c];
  }
}

// ------------------------------------------------------------- GEMM core
__device__ __forceinline__ void gemm_core(
    const unsigned short* __restrict__ A, int lda,
    const unsigned short* __restrict__ BT, int ldb,
    const float* __restrict__ bias,
    unsigned short* __restrict__ C, int ldc, int colOff, int K,
    int m0, int n0) {
  __shared__ __align__(16) unsigned short As[128 * 32];
  __shared__ __align__(16) unsigned short Bs[128 * 32];
  int tid = threadIdx.x;
  int lane = tid & 63, w = tid >> 6;
  int wm = (w >> 1) * 64, wn = (w & 1) * 64;
  int lr = lane & 15, quad = lane >> 4;
  int lgr = lane >> 2;            // row within 16-row staging group
  int lgc = (lane & 3) << 3;      // k-chunk (shorts)
  floatx4 acc[4][4] = {};

  for (int k0 = 0; k0 < K; k0 += 32) {
    __syncthreads();
#pragma unroll
    for (int s = 0; s < 2; s++) {
      int r = w * 16 + s * 64;
      gl_lds16(&A[(size_t)(m0 + r + lgr) * lda + k0 + lgc], &As[r * 32]);
      gl_lds16(&BT[(size_t)(n0 + r + lgr) * ldb + k0 + lgc], &Bs[r * 32]);
    }
    __syncthreads();
    bf16x8 a[4], b[4];
#pragma unroll
    for (int i = 0; i < 4; i++)
      a[i] = *reinterpret_cast<const bf16x8*>(&As[(wm + i * 16 + lr) * 32 + quad * 8]);
#pragma unroll
    for (int j = 0; j < 4; j++)
      b[j] = *reinterpret_cast<const bf16x8*>(&Bs[(wn + j * 16 + lr) * 32 + quad * 8]);
#pragma unroll
    for (int i = 0; i < 4; i++)
#pragma unroll
      for (int j = 0; j < 4; j++)
        acc[i][j] = __builtin_amdgcn_mfma_f32_16x16x32_bf16(a[i], b[j], acc[i][j], 0, 0, 0);
  }
#pragma unroll
  for (int j = 0; j < 4; j++) {
    int gcol = n0 + wn + j * 16 + lr;
    float bv = bias ? bias[gcol] : 0.0f;
#pragma unroll
    for (int i = 0; i < 4; i++) {
#pragma unroll
      for (int r = 0; r < 4; r++) {
        int grow = m0 + wm + i * 16 + quad * 4 + r;
        C[(size_t)grow * ldc + colOff + gcol] = f2b(acc[i][j][r] + bv);
      }
    }
  }
}

// -------- merged: fold GEMMs (96 blocks) + bucket histogram (128 blocks).
// fold: z=0 pos-w4, z=1 aff-w4, z=2 sem (N=512 -> 4x6); hist: node>>4.
__global__ __launch_bounds__(256) void fold_hist(
    const unsigned short* __restrict__ fusT, const unsigned short* __restrict__ wB,
    unsigned short* __restrict__ BTcat,
    const int* __restrict__ pos_idx, const int* __restrict__ aff_idx, int P,
    unsigned* __restrict__ cntB) {
  int blk = blockIdx.x;
  if (blk < 96) {
    int z, bx, by;
    if (blk < 36)      { z = 0; by = blk / 6;        bx = blk % 6; }
    else if (blk < 72) { z = 1; by = (blk - 36) / 6; bx = (blk - 36) % 6; }
    else               { z = 2; by = (blk - 72) / 4; bx = (blk - 72) % 4; }
    gemm_core(fusT + z * 768, 2304, wB + (size_t)z * 589824, 768, nullptr,
              BTcat, 2048, z * 768, 768, by * 128, bx * 128);
  } else {
    __shared__ unsigned lc[NBUK];
    int h = blk - 96;
    int br = h >> 6, b2 = h & 63;
    const int* idx = br ? aff_idx : pos_idx;
    int chunk = (P + 63) / 64;
    int start = b2 * chunk;
    int end = start + chunk;
    if (end > P) end = P;
    int tid = threadIdx.x;
    for (int i = tid; i < NBUK; i += 256) lc[i] = 0u;
    __syncthreads();
    for (int i = start + tid; i < end; i += 256)
      atomicAdd(&lc[idx[i] >> 4], 1u);
    __syncthreads();
    for (int i = tid; i < NBUK; i += 256)
      if (lc[i]) atomicAdd(&cntB[br * NBUK + i], lc[i]);
  }
}

// ------------------------- exclusive scan of 1024 buckets; blockIdx.x = branch
__global__ __launch_bounds__(1024) void scan_bucket(const unsigned* __restrict__ cntB,
                                                    unsigned* __restrict__ offsB,
                                                    unsigned* __restrict__ curB) {
  int br = blockIdx.x;
  __shared__ unsigned ps[NBUK];
  int t = threadIdx.x;
  unsigned v = cntB[br * NBUK + t];
  ps[t] = v;
  __syncthreads();
  for (int off = 1; off < NBUK; off <<= 1) {
    unsigned a = (t >= off) ? ps[t - off] : 0u;
    __syncthreads();
    ps[t] += a;
    __syncthreads();
  }
  unsigned excl = ps[t] - v;
  offsB[br * (NBUK + 1) + t] = excl;
  curB[br * NBUK + t] = excl;
  if (t == NBUK - 1) offsB[br * (NBUK + 1) + NBUK] = ps[t];
}

// ---------------- bucket scatter: per-block LDS count -> reserve -> scatter.
// 8B sorted records {f16 x0, f16 x1, f16 x2, u16 (node&15)}
__global__ __launch_bounds__(256) void bucket_scatter(
    const float* __restrict__ x_pos, const float* __restrict__ x_aff,
    const int* __restrict__ pos_idx, const int* __restrict__ aff_idx, int P,
    unsigned* __restrict__ curB, ushort4* __restrict__ sortedB) {
  __shared__ unsigned lcnt[NBUK], lbase[NBUK];
  int br = blockIdx.y;
  const float* x = br ? x_aff : x_pos;
  const int* idx = br ? aff_idx : pos_idx;
  ushort4* sorted = sortedB + (size_t)br * P;
  int nb = gridDim.x;
  int chunk = (P + nb - 1) / nb;
  int start = blockIdx.x * chunk;
  int end = start + chunk;
  if (end > P) end = P;
  for (int i = threadIdx.x; i < NBUK; i += 256) lcnt[i] = 0u;
  __syncthreads();
  for (int i = start + threadIdx.x; i < end; i += 256)
    atomicAdd(&lcnt[idx[i] >> 4], 1u);
  __syncthreads();
  for (int i = threadIdx.x; i < NBUK; i += 256) {
    unsigned c = lcnt[i];
    lbase[i] = c ? atomicAdd(&curB[br * NBUK + i], c) : 0u;
  }
  __syncthreads();
  for (int i = threadIdx.x; i < NBUK; i += 256) lcnt[i] = 0u;
  __syncthreads();
  for (int i = start + threadIdx.x; i < end; i += 256) {
    int nd = idx[i];
    int b = nd >> 4;
    unsigned lo = atomicAdd(&lcnt[b], 1u);
    ushort4 v;
    v.x = __half_as_ushort(__float2half(x[3 * i]));
    v.y = __half_as_ushort(__float2half(x[3 * i + 1]));
    v.z = __half_as_ushort(__float2half(x[3 * i + 2]));
    v.w = (unsigned short)(nd & 15);
    sorted[lbase[b] + lo] = v;
  }
}

// ---------- per-bucket: folded-LN MLP + MFMA + LDS atomicMax per node-feature
// layer-1 h via packed f16 (v_pk_fma_f16; ReLU via inline v_pk_max_f16),
// layer-2 via mfma_f32_16x16x32_f16.
__global__ __launch_bounds__(256) void bucket_mlp_max(
    const ushort4* __restrict__ sortedB, const unsigned* __restrict__ offsB,
    const __half2* __restrict__ Gp2, const float* __restrict__ Mq2,
    const unsigned short* __restrict__ w2T,
    const float* __restrict__ b2p, const float* __restrict__ b2a,
    unsigned short* __restrict__ xgB, int P) {
  __shared__ __align__(16) unsigned short hs[4][64 * 64];  // 32 KB
  __shared__ unsigned nmaxU[16 * 64];                      // 4 KB
  int br = blockIdx.y;
  int bucket = blockIdx.x;
  const ushort4* sorted = sortedB + (size_t)br * P;
  const unsigned* offs = offsB + br * (NBUK + 1);
  const __half2* Gp = Gp2 + br * 160;
  const float* Mq = Mq2 + br * 16;
  const unsigned short* w2t = w2T + br * 4096;
  const float* b2 = br ? b2a : b2p;
  unsigned short* out = xgB + (size_t)br * NN * 64;

  int tid = threadIdx.x;
  int lane = tid & 63, w = tid >> 6;
  int lr = lane & 15, quad = lane >> 4;
  int l7 = lane & 7;

  for (int e = tid; e < 1024; e += 256) nmaxU[e] = 0u;

  f16x8 bfr[4][2];
#pragma unroll
  for (int j = 0; j < 4; j++)
#pragma unroll
    for (int s = 0; s < 2; s++)
      bfr[j][s] = *reinterpret_cast<const f16x8*>(&w2t[(j * 16 + lr) * 64 + s * 32 + quad * 8]);
  float M00 = Mq[0], M11 = Mq[1], M22 = Mq[2], M33 = Mq[3];
  float T01 = Mq[4], T02 = Mq[5], T03 = Mq[6], T12 = Mq[7], T13 = Mq[8], T23 = Mq[9];
  __syncthreads();

  int seg0 = (int)offs[bucket], seg1 = (int)offs[bucket + 1];
  unsigned short* hrow = &hs[w][0];
  for (int t0 = seg0 + w * 64; t0 < seg1; t0 += 256) {
    int pi = t0 + lane;
    if (pi >= seg1) pi = seg1 - 1;  // duplicate a real point: max-neutral
    ushort4 xv = sorted[pi];
    float x0 = __half2float(__ushort_as_half(xv.x));
    float x1 = __half2float(__ushort_as_half(xv.y));
    float x2 = __half2float(__ushort_as_half(xv.z));
    int ndv = (int)xv.w;
    float var = M33 + x0 * fmaf(M00, x0, fmaf(T01, x1, fmaf(T02, x2, T03)))
                    + x1 * fmaf(M11, x1, fmaf(T12, x2, T13))
                    + x2 * fmaf(M22, x2, T23);
    float rstd = rsqrtf(var + EPS);
    __half2 x0h = __float2half2_rn(x0 * rstd);
    __half2 x1h = __float2half2_rn(x1 * rstd);
    __half2 x2h = __float2half2_rn(x2 * rstd);
    __half2 rsh = __float2half2_rn(rstd);
#pragma unroll
    for (int c = 0; c < 8; c++) {
      unsigned hv[4];
#pragma unroll
      for (int e = 0; e < 4; e++) {
        int k2 = c * 4 + e;
        __half2 y = __hfma2(x0h, Gp[k2],
                    __hfma2(x1h, Gp[32 + k2],
                    __hfma2(x2h, Gp[64 + k2],
                    __hfma2(rsh, Gp[96 + k2], Gp[128 + k2]))));
        unsigned uy = *reinterpret_cast<unsigned*>(&y);
        unsigned ur;
        // packed ReLU: v_pk_max_f16 vs zero register (hoisted v_mov 0)
        asm("v_pk_max_f16 %0, %1, %2" : "=v"(ur) : "v"(uy), "v"(0u));
        hv[e] = ur;
      }
      uint4 pk;
      pk.x = hv[0]; pk.y = hv[1]; pk.z = hv[2]; pk.w = hv[3];
      *reinterpret_cast<uint4*>(&hrow[lane * 64 + ((c ^ l7) << 3)]) = pk;
    }
    asm volatile("s_waitcnt lgkmcnt(0)" ::: "memory");
#pragma unroll
    for (int i = 0; i < 4; i++) {
      int row = i * 16 + lr;
      f16x8 a0 = *reinterpret_cast<const f16x8*>(&hrow[row * 64 + ((quad ^ l7) << 3)]);
      f16x8 a1 = *reinterpret_cast<const f16x8*>(&hrow[row * 64 + (((4 + quad) ^ l7) << 3)]);
      floatx4 accj[4] = {};
#pragma unroll
      for (int j = 0; j < 4; j++) {
        accj[j] = __builtin_amdgcn_mfma_f32_16x16x32_f16(a0, bfr[j][0], accj[j], 0, 0, 0);
        accj[j] = __builtin_amdgcn_mfma_f32_16x16x32_f16(a1, bfr[j][1], accj[j], 0, 0, 0);
      }
      int pb = i * 16 + quad * 4;
      int nd0 = __shfl(ndv, pb + 0, 64);
      int nd1 = __shfl(ndv, pb + 1, 64);
      int nd2 = __shfl(ndv, pb + 2, 64);
      int nd3 = __shfl(ndv, pb + 3, 64);
#pragma unroll
      for (int j = 0; j < 4; j++) {
        int col = j * 16 + lr;
#pragma unroll
        for (int r = 0; r < 4; r++) {
          unsigned u = __float_as_uint(accj[j][r]);
          unsigned ord = u ^ ((unsigned)((int)u >> 31) | 0x80000000u);
          int nd = (r == 0) ? nd0 : (r == 1) ? nd1 : (r == 2) ? nd2 : nd3;
          atomicMax(&nmaxU[nd * 64 + col], ord);
        }
      }
    }
  }
  __syncthreads();
  for (int e = tid; e < 1024; e += 256) {
    unsigned u = nmaxU[e];
    int f = e & 63;
    float val;
    if (u == 0u) val = 0.f;  // empty node
    else {
      float m = (u & 0x80000000u) ? __uint_as_float(u ^ 0x80000000u) : __uint_as_float(~u);
      val = m + b2[f];
    }
    out[(size_t)(bucket * 16 + (e >> 6)) * 64 + f] = f2b(val);
  }
}

// -------- fused w3 GEMM (K=64) + LN(768) + ReLU: 32 full rows per block.
__global__ __launch_bounds__(256) void gemm_w3_ln(
    const unsigned short* __restrict__ xgB, const unsigned short* __restrict__ w3T,
    const float* __restrict__ pb3, const float* __restrict__ ab3,
    const float* __restrict__ pg2, const float* __restrict__ pbe2,
    const float* __restrict__ ag2, const float* __restrict__ abe2,
    unsigned short* __restrict__ tB) {
  __shared__ __align__(16) unsigned short As[32 * 64];  // 4 KB
  __shared__ float pstat[4][32][2];                     // 1 KB
  int br = blockIdx.y;
  const unsigned short* A = xgB + (size_t)br * NN * 64;
  const unsigned short* BT = w3T + (size_t)br * 768 * 64;
  const float* b3 = br ? ab3 : pb3;
  const float* g  = br ? ag2 : pg2;
  const float* be = br ? abe2 : pbe2;
  unsigned short* out = tB + (size_t)br * NN * 768;
  int m0 = blockIdx.x * 32;
  int tid = threadIdx.x;
  int lane = tid & 63, w = tid >> 6;
  int lr = lane & 15, quad = lane >> 4;

  // stage A: each wave moves 1 KB; LDS dest explicitly wave-uniform
  gl_lds16(&A[(size_t)(m0 + (tid >> 3)) * 64 + (tid & 7) * 8], &As[(w << 6) * 8]);
  __syncthreads();

  bf16x8 a[2][2];
#pragma unroll
  for (int i = 0; i < 2; i++)
#pragma unroll
    for (int s = 0; s < 2; s++)
      a[i][s] = *reinterpret_cast<const bf16x8*>(&As[(i * 16 + lr) * 64 + s * 32 + quad * 8]);

  int c0 = w * 192;
  float b3v[12];
#pragma unroll
  for (int nt = 0; nt < 12; nt++) b3v[nt] = b3[c0 + nt * 16 + lr];

  floatx4 acc[2][12] = {};
#pragma unroll
  for (int nt = 0; nt < 12; nt++) {
    int col = c0 + nt * 16 + lr;
    bf16x8 b0 = *reinterpret_cast<const bf16x8*>(&BT[(size_t)col * 64 + quad * 8]);
    bf16x8 b1 = *reinterpret_cast<const bf16x8*>(&BT[(size_t)col * 64 + 32 + quad * 8]);
#pragma unroll
    for (int i = 0; i < 2; i++) {
      acc[i][nt] = __builtin_amdgcn_mfma_f32_16x16x32_bf16(a[i][0], b0, acc[i][nt], 0, 0, 0);
      acc[i][nt] = __builtin_amdgcn_mfma_f32_16x16x32_bf16(a[i][1], b1, acc[i][nt], 0, 0, 0);
    }
  }

  // bias add + per-row partial stats (rows held: i*16 + quad*4 + r)
  float sr[2][4] = {{0.f, 0.f, 0.f, 0.f}, {0.f, 0.f, 0.f, 0.f}};
  float qr[2][4] = {{0.f, 0.f, 0.f, 0.f}, {0.f, 0.f, 0.f, 0.f}};
#pragma unroll
  for (int i = 0; i < 2; i++)
#pragma unroll
    for (int nt = 0; nt < 12; nt++)
#pragma unroll
      for (int r = 0; r < 4; r++) {
        float v = acc[i][nt][r] + b3v[nt];
        acc[i][nt][r] = v;
        sr[i][r] += v;
        qr[i][r] = fmaf(v, v, qr[i][r]);
      }
#pragma unroll
  for (int off = 1; off < 16; off <<= 1) {
#pragma unroll
    for (int i = 0; i < 2; i++)
#pragma unroll
      for (int r = 0; r < 4; r++) {
        sr[i][r] += __shfl_xor(sr[i][r], off, 64);
        qr[i][r] += __shfl_xor(qr[i][r], off, 64);
      }
  }
  if (lr == 0) {
#pragma unroll
    for (int i = 0; i < 2; i++)
#pragma unroll
      for (int r = 0; r < 4; r++) {
        pstat[w][i * 16 + quad * 4 + r][0] = sr[i][r];
        pstat[w][i * 16 + quad * 4 + r][1] = qr[i][r];
      }
  }
  __syncthreads();
  float mrow[2][4], rrow[2][4];
#pragma unroll
  for (int i = 0; i < 2; i++)
#pragma unroll
    for (int r = 0; r < 4; r++) {
      int row = i * 16 + quad * 4 + r;
      float S = pstat[0][row][0] + pstat[1][row][0] + pstat[2][row][0] + pstat[3][row][0];
      float Q = pstat[0][row][1] + pstat[1][row][1] + pstat[2][row][1] + pstat[3][row][1];
      float mm = S * (1.0f / 768.0f);
      float vv = fmaf(-mm, mm, Q * (1.0f / 768.0f));
      mrow[i][r] = mm;
      rrow[i][r] = rsqrtf(vv + EPS);
    }
#pragma unroll
  for (int nt = 0; nt < 12; nt++) {
    int col = c0 + nt * 16 + lr;
    float gv = g[col], bev = be[col];
#pragma unroll
    for (int i = 0; i < 2; i++)
#pragma unroll
      for (int r = 0; r < 4; r++) {
        int row = m0 + i * 16 + quad * 4 + r;
        float y = (acc[i][nt][r] - mrow[i][r]) * rrow[i][r] * gv + bev;
        out[(size_t)row * 768 + col] = f2b(fmaxf(y, 0.0f));
      }
  }
}

// --------------- fused final GEMM v4: virtual K=2048, 128x64 tile, 256 thr,
// 1536 blocks = 6/CU (double the TLP of the 128x128 version: the 2-barrier
// K-step is latency-bound and hidden only by cross-block overlap, m114).
// XCD swizzle: the 12 blocks sharing an m-tile are spaced 8 apart ->
// same XCD -> A refetch served by that L2.
template <int SEMBF>
__global__ __launch_bounds__(256) void gemm_fuse3_v4(
    const unsigned short* __restrict__ A0, const unsigned short* __restrict__ A1,
    const unsigned short* __restrict__ A2b, const float* __restrict__ A2f,
    const unsigned short* __restrict__ BT,
    const float* __restrict__ bias, unsigned short* __restrict__ C) {
  __shared__ __align__(16) unsigned short As[128 * 32];  // 8 KB
  __shared__ __align__(16) unsigned short Bs[64 * 32];   // 4 KB
  int tid = threadIdx.x;
  int lid = blockIdx.x;            // 0..1535
  int sg = lid / 96, rem = lid % 96;
  int n_t = rem >> 3;              // 0..11
  int m_t = sg * 8 + (rem & 7);    // 0..127
  int m0 = m_t * 128, n0 = n_t * 64;
  int lane = tid & 63, w = tid >> 6;
  int wm = w * 32;                 // each wave owns 32 rows x 64 cols
  int lr = lane & 15, quad = lane >> 4;
  int lgr = lane >> 2;
  int lgc = (lane & 3) << 3;
  floatx4 acc[2][4] = {};

  for (int k0 = 0; k0 < 2048; k0 += 32) {
    __syncthreads();
    // B staging: 64 rows, 1 gl_lds per wave (wave w covers rows w*16..w*16+15)
    gl_lds16(&BT[(size_t)(n0 + w * 16 + lgr) * 2048 + k0 + lgc], &Bs[(w * 16) * 32]);
    // A staging: 128 rows, 2 gl_lds per wave
    if (!SEMBF && k0 >= 1536) {
      int kk = k0 - 1536;
#pragma unroll
      for (int s = 0; s < 2; s++) {
        int cc = tid + s * 256;
        int row = cc >> 2, kc = (cc & 3) << 3;
        const float* src = &A2f[(size_t)(m0 + row) * 512 + kk + kc];
        float4 fa = *reinterpret_cast<const float4*>(src);
        float4 fb = *reinterpret_cast<const float4*>(src + 4);
        uint4 pk;
        pk.x = (unsigned)f2b(fa.x) | ((unsigned)f2b(fa.y) << 16);
        pk.y = (unsigned)f2b(fa.z) | ((unsigned)f2b(fa.w) << 16);
        pk.z = (unsigned)f2b(fb.x) | ((unsigned)f2b(fb.y) << 16);
        pk.w = (unsigned)f2b(fb.z) | ((unsigned)f2b(fb.w) << 16);
        *reinterpret_cast<uint4*>(&As[row * 32 + kc]) = pk;
      }
    } else {
      const unsigned short* Ap;
      int kk, ldA;
      if (k0 < 768) { Ap = A0; kk = k0; ldA = 768; }
      else if (k0 < 1536) { Ap = A1; kk = k0 - 768; ldA = 768; }
      else { Ap = A2b; kk = k0 - 1536; ldA = 512; }
#pragma unroll
      for (int s = 0; s < 2; s++) {
        int r = w * 16 + s * 64;
        gl_lds16(&Ap[(size_t)(m0 + r + lgr) * ldA + kk + lgc], &As[r * 32]);
      }
    }
    __syncthreads();
    bf16x8 a[2], b[4];
#pragma unroll
    for (int i = 0; i < 2; i++)
      a[i] = *reinterpret_cast<const bf16x8*>(&As[(wm + i * 16 + lr) * 32 + quad * 8]);
#pragma unroll
    for (int j = 0; j < 4; j++)
      b[j] = *reinterpret_cast<const bf16x8*>(&Bs[(j * 16 + lr) * 32 + quad * 8]);
#pragma unroll
    for (int i = 0; i < 2; i++)
#pragma unroll
      for (int j = 0; j < 4; j++)
        acc[i][j] = __builtin_amdgcn_mfma_f32_16x16x32_bf16(a[i], b[j], acc[i][j], 0, 0, 0);
  }
#pragma unroll
  for (int j = 0; j < 4; j++) {
    int gcol = n0 + j * 16 + lr;
    float bv = bias[gcol];
#pragma unroll
    for (int i = 0; i < 2; i++) {
#pragma unroll
      for (int r = 0; r < 4; r++) {
        int grow = m0 + wm + i * 16 + quad * 4 + r;
        C[(size_t)grow * 768 + gcol] = f2b(acc[i][j][r] + bv);
      }
    }
  }
}

// ------------------------------------- rowwise LN(768)+ReLU, bf16 in/f32 out
__global__ __launch_bounds__(256) void ln_relu_768_f32(
    const unsigned short* __restrict__ X, const float* __restrict__ g,
    const float* __restrict__ be, float* __restrict__ Y) {
  int row = blockIdx.x, tid = threadIdx.x;
  size_t base = (size_t)row * 768;
  float xv[3];
#pragma unroll
  for (int i = 0; i < 3; i++) xv[i] = b2f(X[base + tid + i * 256]);
  float s = xv[0] + xv[1] + xv[2];
  float q = xv[0] * xv[0] + xv[1] * xv[1] + xv[2] * xv[2];
#pragma unroll
  for (int off = 32; off > 0; off >>= 1) {
    s += __shfl_xor(s, off, 64);
    q += __shfl_xor(q, off, 64);
  }
  __shared__ float ss[4], qq[4];
  int w = tid >> 6, lane = tid & 63;
  if (lane == 0) { ss[w] = s; qq[w] = q; }
  __syncthreads();
  s = ss[0] + ss[1] + ss[2] + ss[3];
  q = qq[0] + qq[1] + qq[2] + qq[3];
  float m = s * (1.0f / 768.0f);
  float v = fmaf(-m, m, q * (1.0f / 768.0f));
  float rstd = rsqrtf(v + EPS);
#pragma unroll
  for (int i = 0; i < 3; i++) {
    int c = tid + i * 256;
    float y = (xv[i] - m) * rstd * g[c] + be[c];
    Y[base + c] = fmaxf(y, 0.0f);
  }
}

extern "C" void kernel_launch(void* const* d_in, const int* in_sizes, int n_in,
                              void* d_out, int out_size, void* d_ws, size_t ws_size,
                              hipStream_t stream) {
  typedef const float* cf;
  cf x_pos = (cf)d_in[0];
  const int* pos_idx = (const int*)d_in[1];
  cf x_aff = (cf)d_in[2];
  const int* aff_idx = (const int*)d_in[3];
  cf x_sem = (cf)d_in[4];
  cf pw1 = (cf)d_in[6],  pb1 = (cf)d_in[7],  pg1 = (cf)d_in[8],  pbe1 = (cf)d_in[9];
  cf pw2 = (cf)d_in[10], pb2 = (cf)d_in[11];
  cf pw3 = (cf)d_in[12], pb3 = (cf)d_in[13], pg2 = (cf)d_in[14], pbe2 = (cf)d_in[15];
  cf pw4 = (cf)d_in[16], pb4 = (cf)d_in[17];
  cf aw1 = (cf)d_in[18], ab1 = (cf)d_in[19], ag1 = (cf)d_in[20], abe1 = (cf)d_in[21];
  cf aw2 = (cf)d_in[22], ab2 = (cf)d_in[23];
  cf aw3 = (cf)d_in[24], ab3 = (cf)d_in[25], ag2 = (cf)d_in[26], abe2 = (cf)d_in[27];
  cf aw4 = (cf)d_in[28], ab4 = (cf)d_in[29];
  cf semw = (cf)d_in[30], semb = (cf)d_in[31];
  cf fusw = (cf)d_in[32], fusb = (cf)d_in[33], fusg = (cf)d_in[34], fusbe = (cf)d_in[35];

  int P = in_sizes[0] / 3;

  char* wsb = (char*)d_ws;
  size_t off = 0;
  auto carve = [&](size_t bytes) -> void* {
    void* p = wsb + off;
    off = (off + bytes + 255) & ~(size_t)255;
    return p;
  };
  unsigned short* xgB   = (unsigned short*)carve((size_t)2 * NN * 64 * 2);   // 4 MiB
  unsigned short* t     = (unsigned short*)carve((size_t)2 * NN * 768 * 2);  // 48 MiB
  // carve 2P*16 B so the F alias (NN*768*2 = 24 MiB) always fits even though
  // sorted records are 8 B (uses only the first 2P*8 = 16 MiB)
  ushort4* sorted       = (ushort4*)carve((size_t)2 * P * 16);               // 32 MiB carve
  unsigned short* F = (unsigned short*)sorted;  // alias: sorted dead before fuse3
  unsigned short* w3T   = (unsigned short*)carve((size_t)2 * 768 * 64 * 2);
  unsigned short* fusT  = (unsigned short*)carve((size_t)768 * 2304 * 2);
  unsigned short* wB    = (unsigned short*)carve((size_t)1572864 * 2);       // pw4B|aw4B|semwB
  unsigned short* BTcat = (unsigned short*)carve((size_t)768 * 2048 * 2);
  unsigned short* w2T   = (unsigned short*)carve((size_t)2 * 4096 * 2);
  float* bias_tot = (float*)carve((size_t)768 * 4);
  unsigned* Gp2 = (unsigned*)carve((size_t)2 * 160 * 4);
  float* Mq2 = (float*)carve((size_t)32 * 4);
  unsigned* bcnt  = (unsigned*)carve((size_t)2 * NBUK * 4);
  unsigned* boffs = (unsigned*)carve((size_t)2 * (NBUK + 1) * 4);
  unsigned* bcur  = (unsigned*)carve((size_t)2 * NBUK * 4);
  // semB carved LAST so a too-small workspace only disables the bf16-sem path
  unsigned short* semB = (unsigned short*)carve((size_t)NN * 512 * 2);       // 16 MiB
  bool sem_bf = (off <= ws_size);

  // one mega-launch for all independent preprocessing (7 tasks)
  prep_misc<<<PM_TOT, 256, 0, stream>>>(
      bcnt,
      pw3, aw3, w3T,
      fusw, fusT,
      pw4, aw4, semw, wB,
      x_sem, semB, sem_bf ? 1 : 0,
      pw1, pb1, pg1, pbe1, aw1, ab1, ag1, abe1, pw2, aw2,
      Gp2, Mq2, w2T,
      fusb, pb4, ab4, semb, bias_tot);

  // fold GEMMs (96 blocks) + bucket histogram (128 blocks), one launch
  fold_hist<<<224, 256, 0, stream>>>(fusT, wB, BTcat, pos_idx, aff_idx, P, bcnt);

  scan_bucket<<<2, 1024, 0, stream>>>(bcnt, boffs, bcur);
  bucket_scatter<<<dim3(256, 2), 256, 0, stream>>>(x_pos, x_aff, pos_idx, aff_idx,
                                                   P, bcur, sorted);
  bucket_mlp_max<<<dim3(NBUK, 2), 256, 0, stream>>>(sorted, boffs,
                                                    (const __half2*)Gp2, Mq2,
                                                    w2T, pb2, ab2, xgB, P);

  gemm_w3_ln<<<dim3(NN / 32, 2), 256, 0, stream>>>(xgB, w3T, pb3, ab3,
                                                   pg2, pbe2, ag2, abe2, t);

  if (sem_bf)
    gemm_fuse3_v4<1><<<1536, 256, 0, stream>>>(t, t + (size_t)NN * 768, semB, x_sem,
                                               BTcat, bias_tot, F);
  else
    gemm_fuse3_v4<0><<<1536, 256, 0, stream>>>(t, t + (size_t)NN * 768, nullptr, x_sem,
                                               BTcat, bias_tot, F);
  ln_relu_768_f32<<<NN, 256, 0, stream>>>(F, fusg, fusbe, (float*)d_out);
}

// Round 10
// 431.055 us; speedup vs baseline: 1.1123x; 1.1123x over previous
//
#include <hip/hip_runtime.h>
#include <hip/hip_fp16.h>

typedef __attribute__((ext_vector_type(8))) __bf16 bf16x8;
typedef _Float16 f16x8 __attribute__((ext_vector_type(8)));
typedef __attribute__((ext_vector_type(4))) float floatx4;

#define NN 16384
#define EPS 1e-5f
// bucket = node >> 4 : 16 nodes/bucket, 1024 buckets per branch
#define NBUK 1024

// prep_misc block-range constants
#define PM_ZB 8
#define PM_O1 (PM_ZB)            // 8    : w3 transpose (96)
#define PM_O2 (PM_O1 + 96)       // 104  : fusw transpose (1728)
#define PM_O3 (PM_O2 + 1728)     // 1832 : convert3 (6144)
#define PM_O4 (PM_O3 + 6144)     // 7976 : convert_sem (4096)
#define PM_O5 (PM_O4 + 4096)     // 12072: prep_pointnet (2)
#define PM_O6 (PM_O5 + 2)        // 12074: fuse_bias (768)
#define PM_TOT (PM_O6 + 768)     // 12842

__device__ __forceinline__ unsigned short f2b(float f) {
  unsigned u = __float_as_uint(f);
  u += 0x7fffu + ((u >> 16) & 1u);
  return (unsigned short)(u >> 16);
}
__device__ __forceinline__ float b2f(unsigned short u) {
  return __uint_as_float(((unsigned)u) << 16);
}

// async global->LDS, 16B per lane; LDS dest must be wave-uniform base
// (lane i lands at base + i*16B).
__device__ __forceinline__ void gl_lds16(const void* g, void* l) {
  __builtin_amdgcn_global_load_lds(
      (const __attribute__((address_space(1))) void*)(unsigned long long)g,
      (__attribute__((address_space(3))) void*)(unsigned long long)l, 16, 0, 0);
}

// kept for harness symbol expectations; never launched
__global__ void RoboNodeEncoder_88424786690347_kernel() {}

// ---------------- mega-prep: 7 independent preprocessing tasks, one launch.
// Tasks are block-disjoint; each block takes exactly one branch.
__global__ __launch_bounds__(256) void prep_misc(
    unsigned* __restrict__ bcnt,
    const float* __restrict__ pw3, const float* __restrict__ aw3,
    unsigned short* __restrict__ w3T,
    const float* __restrict__ fusw, unsigned short* __restrict__ fusT,
    const float* __restrict__ pw4, const float* __restrict__ aw4,
    const float* __restrict__ semw, unsigned short* __restrict__ wB,
    const float* __restrict__ x_sem, unsigned short* __restrict__ semB, int do_sem,
    const float* __restrict__ w1p, const float* __restrict__ b1p,
    const float* __restrict__ g1p, const float* __restrict__ be1p,
    const float* __restrict__ w1a, const float* __restrict__ b1a,
    const float* __restrict__ g1a, const float* __restrict__ be1a,
    const float* __restrict__ w2p, const float* __restrict__ w2a,
    unsigned* __restrict__ Gp2, float* __restrict__ Mq2,
    unsigned short* __restrict__ w2T,
    const float* __restrict__ fusb, const float* __restrict__ pb4,
    const float* __restrict__ ab4, const float* __restrict__ semb,
    float* __restrict__ bias_tot) {
  int blk = blockIdx.x;
  int tid = threadIdx.x;

  if (blk < PM_O1) {
    // ---- task 0: zero bcnt (2*NBUK u32)
    int i = blk * 256 + tid;
    if (i < 2 * NBUK) bcnt[i] = 0u;

  } else if (blk < PM_O2) {
    // ---- task 1: w3 transpose pair (R=64, C=768), 96 blocks
    __shared__ float t[32][33];
    int idx = blk - PM_O1;
    int z = idx / 48, rem = idx % 48, Y = rem / 24, X = rem % 24;
    const float* in = z ? aw3 : pw3;
    unsigned short* out = w3T + (size_t)z * 768 * 64;
    int bx = X * 32, by = Y * 32;
    int x = tid & 31, y = tid >> 5;
#pragma unroll
    for (int i = 0; i < 32; i += 8) t[y + i][x] = in[(size_t)(by + y + i) * 768 + bx + x];
    __syncthreads();
#pragma unroll
    for (int i = 0; i < 32; i += 8) out[(size_t)(bx + y + i) * 64 + by + x] = f2b(t[x][y + i]);

  } else if (blk < PM_O3) {
    // ---- task 2: fusw transpose (R=2304, C=768), 1728 blocks
    __shared__ float t[32][33];
    int idx = blk - PM_O2;
    int X = idx % 24, Y = idx / 24;
    int bx = X * 32, by = Y * 32;
    int x = tid & 31, y = tid >> 5;
#pragma unroll
    for (int i = 0; i < 32; i += 8) t[y + i][x] = fusw[(size_t)(by + y + i) * 768 + bx + x];
    __syncthreads();
#pragma unroll
    for (int i = 0; i < 32; i += 8) fusT[(size_t)(bx + y + i) * 2304 + by + x] = f2b(t[x][y + i]);

  } else if (blk < PM_O4) {
    // ---- task 3: convert3 (pw4|aw4|semw -> bf16 wB), 6144 blocks
    int i = (blk - PM_O3) * 256 + tid;
    float v;
    if (i < 589824) v = pw4[i];
    else if (i < 1179648) v = aw4[i - 589824];
    else v = semw[i - 1179648];
    wB[i] = f2b(v);

  } else if (blk < PM_O5) {
    // ---- task 4: convert_sem (f32 -> bf16, 8/thread), 4096 blocks
    if (!do_sem) return;
    int i = (blk - PM_O4) * 256 + tid;
    const float4* p = reinterpret_cast<const float4*>(x_sem);
    float4 fa = p[2 * i];
    float4 fb = p[2 * i + 1];
    uint4 pk;
    pk.x = (unsigned)f2b(fa.x) | ((unsigned)f2b(fa.y) << 16);
    pk.y = (unsigned)f2b(fa.z) | ((unsigned)f2b(fa.w) << 16);
    pk.z = (unsigned)f2b(fb.x) | ((unsigned)f2b(fb.y) << 16);
    pk.w = (unsigned)f2b(fb.z) | ((unsigned)f2b(fb.w) << 16);
    reinterpret_cast<uint4*>(semB)[i] = pk;

  } else if (blk < PM_O6) {
    // ---- task 5: prep_pointnet (folded-LN consts, f16 packs), 2 blocks
    if (tid >= 64) return;
    int br = blk - PM_O5;
    const float* w1 = br ? w1a : w1p;
    const float* b1 = br ? b1a : b1p;
    const float* g1 = br ? g1a : g1p;
    const float* be1 = br ? be1a : be1p;
    const float* w2 = br ? w2a : w2p;
    unsigned* Gp = Gp2 + br * 160;
    float* Mq = Mq2 + br * 16;
    unsigned short* w2t = w2T + br * 4096;
    int k = tid;
#pragma unroll
    for (int n = 0; n < 64; n++)
      w2t[n * 64 + k] = __half_as_ushort(__float2half(w2[k * 64 + n]));
    float c[4] = {w1[k], w1[64 + k], w1[128 + k], b1[k]};
#pragma unroll
    for (int a = 0; a < 4; a++) {
      float s = c[a];
#pragma unroll
      for (int off = 32; off > 0; off >>= 1) s += __shfl_xor(s, off, 64);
      c[a] -= s * (1.f / 64.f);
    }
    float g = g1[k];
#pragma unroll
    for (int a = 0; a < 4; a++) {
      float Ga = c[a] * g;
      float Gb = __shfl_down(Ga, 1, 64);
      if (!(k & 1))
        Gp[a * 32 + (k >> 1)] =
            (unsigned)__half_as_ushort(__float2half(Ga)) |
            ((unsigned)__half_as_ushort(__float2half(Gb)) << 16);
    }
    {
      float Ba = be1[k];
      float Bb = __shfl_down(Ba, 1, 64);
      if (!(k & 1))
        Gp[128 + (k >> 1)] =
            (unsigned)__half_as_ushort(__float2half(Ba)) |
            ((unsigned)__half_as_ushort(__float2half(Bb)) << 16);
    }
    const int AA[10] = {0, 1, 2, 3, 0, 0, 0, 1, 1, 2};
    const int BB[10] = {0, 1, 2, 3, 1, 2, 3, 2, 3, 3};
#pragma unroll
    for (int t = 0; t < 10; t++) {
      float s = c[AA[t]] * c[BB[t]];
#pragma unroll
      for (int off = 32; off > 0; off >>= 1) s += __shfl_xor(s, off, 64);
      s *= (1.f / 64.f);
      if (t >= 4) s *= 2.f;
      if (k == 0) Mq[t] = s;
    }

  } else {
    // ---- task 6: fuse_bias (fold upstream biases), 768 blocks
    __shared__ float sm[4];
    int c = blk - PM_O6;
    float s = 0.f;
    for (int j = tid; j < 768; j += 256) {
      s = fmaf(pb4[j],  fusw[(size_t)j * 768 + c], s);
      s = fmaf(ab4[j],  fusw[(size_t)(768 + j) * 768 + c], s);
      s = fmaf(semb[j], fusw[(size_t)(1536 + j) * 768 + c], s);
    }
#pragma unroll
    for (int off = 32; off > 0; off >>= 1) s += __shfl_xor(s, off, 64);
    if ((tid & 63) == 0) sm[tid >> 6] = s;
    __syncthreads();
    if (tid == 0) bias_tot[c] = sm[0] + sm[1] + sm[2] + sm[3] + fusb[c];
  }
}

// ------------------------------------------------------------- GEMM core
__device__ __forceinline__ void gemm_core(
    const unsigned short* __restrict__ A, int lda,
    const unsigned short* __restrict__ BT, int ldb,
    const float* __restrict__ bias,
    unsigned short* __restrict__ C, int ldc, int colOff, int K,
    int m0, int n0) {
  __shared__ __align__(16) unsigned short As[128 * 32];
  __shared__ __align__(16) unsigned short Bs[128 * 32];
  int tid = threadIdx.x;
  int lane = tid & 63, w = tid >> 6;
  int wm = (w >> 1) * 64, wn = (w & 1) * 64;
  int lr = lane & 15, quad = lane >> 4;
  int lgr = lane >> 2;            // row within 16-row staging group
  int lgc = (lane & 3) << 3;      // k-chunk (shorts)
  floatx4 acc[4][4] = {};

  for (int k0 = 0; k0 < K; k0 += 32) {
    __syncthreads();
#pragma unroll
    for (int s = 0; s < 2; s++) {
      int r = w * 16 + s * 64;
      gl_lds16(&A[(size_t)(m0 + r + lgr) * lda + k0 + lgc], &As[r * 32]);
      gl_lds16(&BT[(size_t)(n0 + r + lgr) * ldb + k0 + lgc], &Bs[r * 32]);
    }
    __syncthreads();
    bf16x8 a[4], b[4];
#pragma unroll
    for (int i = 0; i < 4; i++)
      a[i] = *reinterpret_cast<const bf16x8*>(&As[(wm + i * 16 + lr) * 32 + quad * 8]);
#pragma unroll
    for (int j = 0; j < 4; j++)
      b[j] = *reinterpret_cast<const bf16x8*>(&Bs[(wn + j * 16 + lr) * 32 + quad * 8]);
#pragma unroll
    for (int i = 0; i < 4; i++)
#pragma unroll
      for (int j = 0; j < 4; j++)
        acc[i][j] = __builtin_amdgcn_mfma_f32_16x16x32_bf16(a[i], b[j], acc[i][j], 0, 0, 0);
  }
#pragma unroll
  for (int j = 0; j < 4; j++) {
    int gcol = n0 + wn + j * 16 + lr;
    float bv = bias ? bias[gcol] : 0.0f;
#pragma unroll
    for (int i = 0; i < 4; i++) {
#pragma unroll
      for (int r = 0; r < 4; r++) {
        int grow = m0 + wm + i * 16 + quad * 4 + r;
        C[(size_t)grow * ldc + colOff + gcol] = f2b(acc[i][j][r] + bv);
      }
    }
  }
}

// -------- merged: fold GEMMs (96 blocks) + bucket histogram (128 blocks).
// fold: z=0 pos-w4, z=1 aff-w4, z=2 sem (N=512 -> 4x6); hist: node>>4.
__global__ __launch_bounds__(256) void fold_hist(
    const unsigned short* __restrict__ fusT, const unsigned short* __restrict__ wB,
    unsigned short* __restrict__ BTcat,
    const int* __restrict__ pos_idx, const int* __restrict__ aff_idx, int P,
    unsigned* __restrict__ cntB) {
  int blk = blockIdx.x;
  if (blk < 96) {
    int z, bx, by;
    if (blk < 36)      { z = 0; by = blk / 6;        bx = blk % 6; }
    else if (blk < 72) { z = 1; by = (blk - 36) / 6; bx = (blk - 36) % 6; }
    else               { z = 2; by = (blk - 72) / 4; bx = (blk - 72) % 4; }
    gemm_core(fusT + z * 768, 2304, wB + (size_t)z * 589824, 768, nullptr,
              BTcat, 2048, z * 768, 768, by * 128, bx * 128);
  } else {
    __shared__ unsigned lc[NBUK];
    int h = blk - 96;
    int br = h >> 6, b2 = h & 63;
    const int* idx = br ? aff_idx : pos_idx;
    int chunk = (P + 63) / 64;
    int start = b2 * chunk;
    int end = start + chunk;
    if (end > P) end = P;
    int tid = threadIdx.x;
    for (int i = tid; i < NBUK; i += 256) lc[i] = 0u;
    __syncthreads();
    for (int i = start + tid; i < end; i += 256)
      atomicAdd(&lc[idx[i] >> 4], 1u);
    __syncthreads();
    for (int i = tid; i < NBUK; i += 256)
      if (lc[i]) atomicAdd(&cntB[br * NBUK + i], lc[i]);
  }
}

// ------------------------- exclusive scan of 1024 buckets; blockIdx.x = branch
__global__ __launch_bounds__(1024) void scan_bucket(const unsigned* __restrict__ cntB,
                                                    unsigned* __restrict__ offsB,
                                                    unsigned* __restrict__ curB) {
  int br = blockIdx.x;
  __shared__ unsigned ps[NBUK];
  int t = threadIdx.x;
  unsigned v = cntB[br * NBUK + t];
  ps[t] = v;
  __syncthreads();
  for (int off = 1; off < NBUK; off <<= 1) {
    unsigned a = (t >= off) ? ps[t - off] : 0u;
    __syncthreads();
    ps[t] += a;
    __syncthreads();
  }
  unsigned excl = ps[t] - v;
  offsB[br * (NBUK + 1) + t] = excl;
  curB[br * NBUK + t] = excl;
  if (t == NBUK - 1) offsB[br * (NBUK + 1) + NBUK] = ps[t];
}

// ---------------- bucket scatter: per-block LDS count -> reserve -> scatter.
// 8B sorted records {f16 x0, f16 x1, f16 x2, u16 (node&15)}
__global__ __launch_bounds__(256) void bucket_scatter(
    const float* __restrict__ x_pos, const float* __restrict__ x_aff,
    const int* __restrict__ pos_idx, const int* __restrict__ aff_idx, int P,
    unsigned* __restrict__ curB, ushort4* __restrict__ sortedB) {
  __shared__ unsigned lcnt[NBUK], lbase[NBUK];
  int br = blockIdx.y;
  const float* x = br ? x_aff : x_pos;
  const int* idx = br ? aff_idx : pos_idx;
  ushort4* sorted = sortedB + (size_t)br * P;
  int nb = gridDim.x;
  int chunk = (P + nb - 1) / nb;
  int start = blockIdx.x * chunk;
  int end = start + chunk;
  if (end > P) end = P;
  for (int i = threadIdx.x; i < NBUK; i += 256) lcnt[i] = 0u;
  __syncthreads();
  for (int i = start + threadIdx.x; i < end; i += 256)
    atomicAdd(&lcnt[idx[i] >> 4], 1u);
  __syncthreads();
  for (int i = threadIdx.x; i < NBUK; i += 256) {
    unsigned c = lcnt[i];
    lbase[i] = c ? atomicAdd(&curB[br * NBUK + i], c) : 0u;
  }
  __syncthreads();
  for (int i = threadIdx.x; i < NBUK; i += 256) lcnt[i] = 0u;
  __syncthreads();
  for (int i = start + threadIdx.x; i < end; i += 256) {
    int nd = idx[i];
    int b = nd >> 4;
    unsigned lo = atomicAdd(&lcnt[b], 1u);
    ushort4 v;
    v.x = __half_as_ushort(__float2half(x[3 * i]));
    v.y = __half_as_ushort(__float2half(x[3 * i + 1]));
    v.z = __half_as_ushort(__float2half(x[3 * i + 2]));
    v.w = (unsigned short)(nd & 15);
    sorted[lbase[b] + lo] = v;
  }
}

// ---------- per-bucket: folded-LN MLP + MFMA + LDS atomicMax per node-feature
// layer-1 h via packed f16 (v_pk_fma_f16; ReLU via inline v_pk_max_f16),
// layer-2 via mfma_f32_16x16x32_f16.
__global__ __launch_bounds__(256) void bucket_mlp_max(
    const ushort4* __restrict__ sortedB, const unsigned* __restrict__ offsB,
    const __half2* __restrict__ Gp2, const float* __restrict__ Mq2,
    const unsigned short* __restrict__ w2T,
    const float* __restrict__ b2p, const float* __restrict__ b2a,
    unsigned short* __restrict__ xgB, int P) {
  __shared__ __align__(16) unsigned short hs[4][64 * 64];  // 32 KB
  __shared__ unsigned nmaxU[16 * 64];                      // 4 KB
  int br = blockIdx.y;
  int bucket = blockIdx.x;
  const ushort4* sorted = sortedB + (size_t)br * P;
  const unsigned* offs = offsB + br * (NBUK + 1);
  const __half2* Gp = Gp2 + br * 160;
  const float* Mq = Mq2 + br * 16;
  const unsigned short* w2t = w2T + br * 4096;
  const float* b2 = br ? b2a : b2p;
  unsigned short* out = xgB + (size_t)br * NN * 64;

  int tid = threadIdx.x;
  int lane = tid & 63, w = tid >> 6;
  int lr = lane & 15, quad = lane >> 4;
  int l7 = lane & 7;

  for (int e = tid; e < 1024; e += 256) nmaxU[e] = 0u;

  f16x8 bfr[4][2];
#pragma unroll
  for (int j = 0; j < 4; j++)
#pragma unroll
    for (int s = 0; s < 2; s++)
      bfr[j][s] = *reinterpret_cast<const f16x8*>(&w2t[(j * 16 + lr) * 64 + s * 32 + quad * 8]);
  float M00 = Mq[0], M11 = Mq[1], M22 = Mq[2], M33 = Mq[3];
  float T01 = Mq[4], T02 = Mq[5], T03 = Mq[6], T12 = Mq[7], T13 = Mq[8], T23 = Mq[9];
  __syncthreads();

  int seg0 = (int)offs[bucket], seg1 = (int)offs[bucket + 1];
  unsigned short* hrow = &hs[w][0];
  for (int t0 = seg0 + w * 64; t0 < seg1; t0 += 256) {
    int pi = t0 + lane;
    if (pi >= seg1) pi = seg1 - 1;  // duplicate a real point: max-neutral
    ushort4 xv = sorted[pi];
    float x0 = __half2float(__ushort_as_half(xv.x));
    float x1 = __half2float(__ushort_as_half(xv.y));
    float x2 = __half2float(__ushort_as_half(xv.z));
    int ndv = (int)xv.w;
    float var = M33 + x0 * fmaf(M00, x0, fmaf(T01, x1, fmaf(T02, x2, T03)))
                    + x1 * fmaf(M11, x1, fmaf(T12, x2, T13))
                    + x2 * fmaf(M22, x2, T23);
    float rstd = rsqrtf(var + EPS);
    __half2 x0h = __float2half2_rn(x0 * rstd);
    __half2 x1h = __float2half2_rn(x1 * rstd);
    __half2 x2h = __float2half2_rn(x2 * rstd);
    __half2 rsh = __float2half2_rn(rstd);
#pragma unroll
    for (int c = 0; c < 8; c++) {
      unsigned hv[4];
#pragma unroll
      for (int e = 0; e < 4; e++) {
        int k2 = c * 4 + e;
        __half2 y = __hfma2(x0h, Gp[k2],
                    __hfma2(x1h, Gp[32 + k2],
                    __hfma2(x2h, Gp[64 + k2],
                    __hfma2(rsh, Gp[96 + k2], Gp[128 + k2]))));
        unsigned uy = *reinterpret_cast<unsigned*>(&y);
        unsigned ur;
        // packed ReLU: v_pk_max_f16 vs zero register (hoisted v_mov 0)
        asm("v_pk_max_f16 %0, %1, %2" : "=v"(ur) : "v"(uy), "v"(0u));
        hv[e] = ur;
      }
      uint4 pk;
      pk.x = hv[0]; pk.y = hv[1]; pk.z = hv[2]; pk.w = hv[3];
      *reinterpret_cast<uint4*>(&hrow[lane * 64 + ((c ^ l7) << 3)]) = pk;
    }
    asm volatile("s_waitcnt lgkmcnt(0)" ::: "memory");
#pragma unroll
    for (int i = 0; i < 4; i++) {
      int row = i * 16 + lr;
      f16x8 a0 = *reinterpret_cast<const f16x8*>(&hrow[row * 64 + ((quad ^ l7) << 3)]);
      f16x8 a1 = *reinterpret_cast<const f16x8*>(&hrow[row * 64 + (((4 + quad) ^ l7) << 3)]);
      floatx4 accj[4] = {};
#pragma unroll
      for (int j = 0; j < 4; j++) {
        accj[j] = __builtin_amdgcn_mfma_f32_16x16x32_f16(a0, bfr[j][0], accj[j], 0, 0, 0);
        accj[j] = __builtin_amdgcn_mfma_f32_16x16x32_f16(a1, bfr[j][1], accj[j], 0, 0, 0);
      }
      int pb = i * 16 + quad * 4;
      int nd0 = __shfl(ndv, pb + 0, 64);
      int nd1 = __shfl(ndv, pb + 1, 64);
      int nd2 = __shfl(ndv, pb + 2, 64);
      int nd3 = __shfl(ndv, pb + 3, 64);
#pragma unroll
      for (int j = 0; j < 4; j++) {
        int col = j * 16 + lr;
#pragma unroll
        for (int r = 0; r < 4; r++) {
          unsigned u = __float_as_uint(accj[j][r]);
          unsigned ord = u ^ ((unsigned)((int)u >> 31) | 0x80000000u);
          int nd = (r == 0) ? nd0 : (r == 1) ? nd1 : (r == 2) ? nd2 : nd3;
          atomicMax(&nmaxU[nd * 64 + col], ord);
        }
      }
    }
  }
  __syncthreads();
  for (int e = tid; e < 1024; e += 256) {
    unsigned u = nmaxU[e];
    int f = e & 63;
    float val;
    if (u == 0u) val = 0.f;  // empty node
    else {
      float m = (u & 0x80000000u) ? __uint_as_float(u ^ 0x80000000u) : __uint_as_float(~u);
      val = m + b2[f];
    }
    out[(size_t)(bucket * 16 + (e >> 6)) * 64 + f] = f2b(val);
  }
}

// -------- fused w3 GEMM (K=64) + LN(768) + ReLU: 32 full rows per block.
__global__ __launch_bounds__(256) void gemm_w3_ln(
    const unsigned short* __restrict__ xgB, const unsigned short* __restrict__ w3T,
    const float* __restrict__ pb3, const float* __restrict__ ab3,
    const float* __restrict__ pg2, const float* __restrict__ pbe2,
    const float* __restrict__ ag2, const float* __restrict__ abe2,
    unsigned short* __restrict__ tB) {
  __shared__ __align__(16) unsigned short As[32 * 64];  // 4 KB
  __shared__ float pstat[4][32][2];                     // 1 KB
  int br = blockIdx.y;
  const unsigned short* A = xgB + (size_t)br * NN * 64;
  const unsigned short* BT = w3T + (size_t)br * 768 * 64;
  const float* b3 = br ? ab3 : pb3;
  const float* g  = br ? ag2 : pg2;
  const float* be = br ? abe2 : pbe2;
  unsigned short* out = tB + (size_t)br * NN * 768;
  int m0 = blockIdx.x * 32;
  int tid = threadIdx.x;
  int lane = tid & 63, w = tid >> 6;
  int lr = lane & 15, quad = lane >> 4;

  // stage A: each wave moves 1 KB; LDS dest explicitly wave-uniform
  gl_lds16(&A[(size_t)(m0 + (tid >> 3)) * 64 + (tid & 7) * 8], &As[(w << 6) * 8]);
  __syncthreads();

  bf16x8 a[2][2];
#pragma unroll
  for (int i = 0; i < 2; i++)
#pragma unroll
    for (int s = 0; s < 2; s++)
      a[i][s] = *reinterpret_cast<const bf16x8*>(&As[(i * 16 + lr) * 64 + s * 32 + quad * 8]);

  int c0 = w * 192;
  float b3v[12];
#pragma unroll
  for (int nt = 0; nt < 12; nt++) b3v[nt] = b3[c0 + nt * 16 + lr];

  floatx4 acc[2][12] = {};
#pragma unroll
  for (int nt = 0; nt < 12; nt++) {
    int col = c0 + nt * 16 + lr;
    bf16x8 b0 = *reinterpret_cast<const bf16x8*>(&BT[(size_t)col * 64 + quad * 8]);
    bf16x8 b1 = *reinterpret_cast<const bf16x8*>(&BT[(size_t)col * 64 + 32 + quad * 8]);
#pragma unroll
    for (int i = 0; i < 2; i++) {
      acc[i][nt] = __builtin_amdgcn_mfma_f32_16x16x32_bf16(a[i][0], b0, acc[i][nt], 0, 0, 0);
      acc[i][nt] = __builtin_amdgcn_mfma_f32_16x16x32_bf16(a[i][1], b1, acc[i][nt], 0, 0, 0);
    }
  }

  // bias add + per-row partial stats (rows held: i*16 + quad*4 + r)
  float sr[2][4] = {{0.f, 0.f, 0.f, 0.f}, {0.f, 0.f, 0.f, 0.f}};
  float qr[2][4] = {{0.f, 0.f, 0.f, 0.f}, {0.f, 0.f, 0.f, 0.f}};
#pragma unroll
  for (int i = 0; i < 2; i++)
#pragma unroll
    for (int nt = 0; nt < 12; nt++)
#pragma unroll
      for (int r = 0; r < 4; r++) {
        float v = acc[i][nt][r] + b3v[nt];
        acc[i][nt][r] = v;
        sr[i][r] += v;
        qr[i][r] = fmaf(v, v, qr[i][r]);
      }
#pragma unroll
  for (int off = 1; off < 16; off <<= 1) {
#pragma unroll
    for (int i = 0; i < 2; i++)
#pragma unroll
      for (int r = 0; r < 4; r++) {
        sr[i][r] += __shfl_xor(sr[i][r], off, 64);
        qr[i][r] += __shfl_xor(qr[i][r], off, 64);
      }
  }
  if (lr == 0) {
#pragma unroll
    for (int i = 0; i < 2; i++)
#pragma unroll
      for (int r = 0; r < 4; r++) {
        pstat[w][i * 16 + quad * 4 + r][0] = sr[i][r];
        pstat[w][i * 16 + quad * 4 + r][1] = qr[i][r];
      }
  }
  __syncthreads();
  float mrow[2][4], rrow[2][4];
#pragma unroll
  for (int i = 0; i < 2; i++)
#pragma unroll
    for (int r = 0; r < 4; r++) {
      int row = i * 16 + quad * 4 + r;
      float S = pstat[0][row][0] + pstat[1][row][0] + pstat[2][row][0] + pstat[3][row][0];
      float Q = pstat[0][row][1] + pstat[1][row][1] + pstat[2][row][1] + pstat[3][row][1];
      float mm = S * (1.0f / 768.0f);
      float vv = fmaf(-mm, mm, Q * (1.0f / 768.0f));
      mrow[i][r] = mm;
      rrow[i][r] = rsqrtf(vv + EPS);
    }
#pragma unroll
  for (int nt = 0; nt < 12; nt++) {
    int col = c0 + nt * 16 + lr;
    float gv = g[col], bev = be[col];
#pragma unroll
    for (int i = 0; i < 2; i++)
#pragma unroll
      for (int r = 0; r < 4; r++) {
        int row = m0 + i * 16 + quad * 4 + r;
        float y = (acc[i][nt][r] - mrow[i][r]) * rrow[i][r] * gv + bev;
        out[(size_t)row * 768 + col] = f2b(fmaxf(y, 0.0f));
      }
  }
}

// --------------- fused final GEMM v5: virtual K=2048, 128x128 tile, BK=64,
// 768 blocks, same 2-barrier structure as the proven v2 but 2x MFMA per
// barrier (32/wave) and half the K-steps (32): amortizes the barrier drain.
// LDS rows are 128B -> full-wave bank conflict without mitigation; fixed by
// the both-sides involution swizzle (rule #21): linear LDS dest, pre-swizzled
// global SOURCE chunk ((lane&7)^(lane>>3)), matching XOR on fragment reads.
template <int SEMBF>
__global__ __launch_bounds__(256) void gemm_fuse3_v5(
    const unsigned short* __restrict__ A0, const unsigned short* __restrict__ A1,
    const unsigned short* __restrict__ A2b, const float* __restrict__ A2f,
    const unsigned short* __restrict__ BT,
    const float* __restrict__ bias, unsigned short* __restrict__ C) {
  __shared__ __align__(16) unsigned short As[128 * 64];  // 16 KB
  __shared__ __align__(16) unsigned short Bs[128 * 64];  // 16 KB
  int tid = threadIdx.x;
  int lid = blockIdx.x;            // 0..767
  int sg = lid / 48, rem = lid % 48;
  int n_t = rem >> 3;              // 0..5
  int m_t = sg * 8 + (rem & 7);    // 0..127
  int m0 = m_t * 128, n0 = n_t * 128;
  int lane = tid & 63, w = tid >> 6;
  int wm = (w >> 1) * 64, wn = (w & 1) * 64;
  int lr = lane & 15, quad = lane >> 4;
  int l7 = lane & 7;
  int lgr8 = lane >> 3;                       // row within 8-row segment
  int lgc8 = ((lane & 7) ^ lgr8) << 3;        // swizzled source chunk (shorts)
  floatx4 acc[4][4] = {};

  for (int k0 = 0; k0 < 2048; k0 += 64) {
    __syncthreads();
    // B staging: 128 rows = 16 segments of 8 rows; 4 per wave
#pragma unroll
    for (int s = 0; s < 4; s++) {
      int r = (w * 4 + s) * 8;
      gl_lds16(&BT[(size_t)(n0 + r + lgr8) * 2048 + k0 + lgc8], &Bs[r * 64]);
    }
    // A staging
    if (!SEMBF && k0 >= 1536) {
      int kk = k0 - 1536;
#pragma unroll
      for (int s = 0; s < 4; s++) {
        int cc = tid + s * 256;
        int row = cc >> 3, c = cc & 7;
        const float* src = &A2f[(size_t)(m0 + row) * 512 + kk + c * 8];
        float4 fa = *reinterpret_cast<const float4*>(src);
        float4 fb = *reinterpret_cast<const float4*>(src + 4);
        uint4 pk;
        pk.x = (unsigned)f2b(fa.x) | ((unsigned)f2b(fa.y) << 16);
        pk.y = (unsigned)f2b(fa.z) | ((unsigned)f2b(fa.w) << 16);
        pk.z = (unsigned)f2b(fb.x) | ((unsigned)f2b(fb.y) << 16);
        pk.w = (unsigned)f2b(fb.z) | ((unsigned)f2b(fb.w) << 16);
        // same involution on the register-staged write
        *reinterpret_cast<uint4*>(&As[row * 64 + ((c ^ (row & 7)) << 3)]) = pk;
      }
    } else {
      const unsigned short* Ap;
      int kk, ldA;
      if (k0 < 768) { Ap = A0; kk = k0; ldA = 768; }
      else if (k0 < 1536) { Ap = A1; kk = k0 - 768; ldA = 768; }
      else { Ap = A2b; kk = k0 - 1536; ldA = 512; }
#pragma unroll
      for (int s = 0; s < 4; s++) {
        int r = (w * 4 + s) * 8;
        gl_lds16(&Ap[(size_t)(m0 + r + lgr8) * ldA + kk + lgc8], &As[r * 64]);
      }
    }
    __syncthreads();
#pragma unroll
    for (int ks = 0; ks < 2; ks++) {
      bf16x8 a[4], b[4];
      int cs = ks << 2;
#pragma unroll
      for (int i = 0; i < 4; i++)
        a[i] = *reinterpret_cast<const bf16x8*>(
            &As[(wm + i * 16 + lr) * 64 + (((cs + quad) ^ l7) << 3)]);
#pragma unroll
      for (int j = 0; j < 4; j++)
        b[j] = *reinterpret_cast<const bf16x8*>(
            &Bs[(wn + j * 16 + lr) * 64 + (((cs + quad) ^ l7) << 3)]);
#pragma unroll
      for (int i = 0; i < 4; i++)
#pragma unroll
        for (int j = 0; j < 4; j++)
          acc[i][j] = __builtin_amdgcn_mfma_f32_16x16x32_bf16(a[i], b[j], acc[i][j], 0, 0, 0);
    }
  }
#pragma unroll
  for (int j = 0; j < 4; j++) {
    int gcol = n0 + wn + j * 16 + lr;
    float bv = bias[gcol];
#pragma unroll
    for (int i = 0; i < 4; i++) {
#pragma unroll
      for (int r = 0; r < 4; r++) {
        int grow = m0 + wm + i * 16 + quad * 4 + r;
        C[(size_t)grow * 768 + gcol] = f2b(acc[i][j][r] + bv);
      }
    }
  }
}

// ------------------------------------- rowwise LN(768)+ReLU, bf16 in/f32 out
__global__ __launch_bounds__(256) void ln_relu_768_f32(
    const unsigned short* __restrict__ X, const float* __restrict__ g,
    const float* __restrict__ be, float* __restrict__ Y) {
  int row = blockIdx.x, tid = threadIdx.x;
  size_t base = (size_t)row * 768;
  float xv[3];
#pragma unroll
  for (int i = 0; i < 3; i++) xv[i] = b2f(X[base + tid + i * 256]);
  float s = xv[0] + xv[1] + xv[2];
  float q = xv[0] * xv[0] + xv[1] * xv[1] + xv[2] * xv[2];
#pragma unroll
  for (int off = 32; off > 0; off >>= 1) {
    s += __shfl_xor(s, off, 64);
    q += __shfl_xor(q, off, 64);
  }
  __shared__ float ss[4], qq[4];
  int w = tid >> 6, lane = tid & 63;
  if (lane == 0) { ss[w] = s; qq[w] = q; }
  __syncthreads();
  s = ss[0] + ss[1] + ss[2] + ss[3];
  q = qq[0] + qq[1] + qq[2] + qq[3];
  float m = s * (1.0f / 768.0f);
  float v = fmaf(-m, m, q * (1.0f / 768.0f));
  float rstd = rsqrtf(v + EPS);
#pragma unroll
  for (int i = 0; i < 3; i++) {
    int c = tid + i * 256;
    float y = (xv[i] - m) * rstd * g[c] + be[c];
    Y[base + c] = fmaxf(y, 0.0f);
  }
}

extern "C" void kernel_launch(void* const* d_in, const int* in_sizes, int n_in,
                              void* d_out, int out_size, void* d_ws, size_t ws_size,
                              hipStream_t stream) {
  typedef const float* cf;
  cf x_pos = (cf)d_in[0];
  const int* pos_idx = (const int*)d_in[1];
  cf x_aff = (cf)d_in[2];
  const int* aff_idx = (const int*)d_in[3];
  cf x_sem = (cf)d_in[4];
  cf pw1 = (cf)d_in[6],  pb1 = (cf)d_in[7],  pg1 = (cf)d_in[8],  pbe1 = (cf)d_in[9];
  cf pw2 = (cf)d_in[10], pb2 = (cf)d_in[11];
  cf pw3 = (cf)d_in[12], pb3 = (cf)d_in[13], pg2 = (cf)d_in[14], pbe2 = (cf)d_in[15];
  cf pw4 = (cf)d_in[16], pb4 = (cf)d_in[17];
  cf aw1 = (cf)d_in[18], ab1 = (cf)d_in[19], ag1 = (cf)d_in[20], abe1 = (cf)d_in[21];
  cf aw2 = (cf)d_in[22], ab2 = (cf)d_in[23];
  cf aw3 = (cf)d_in[24], ab3 = (cf)d_in[25], ag2 = (cf)d_in[26], abe2 = (cf)d_in[27];
  cf aw4 = (cf)d_in[28], ab4 = (cf)d_in[29];
  cf semw = (cf)d_in[30], semb = (cf)d_in[31];
  cf fusw = (cf)d_in[32], fusb = (cf)d_in[33], fusg = (cf)d_in[34], fusbe = (cf)d_in[35];

  int P = in_sizes[0] / 3;

  char* wsb = (char*)d_ws;
  size_t off = 0;
  auto carve = [&](size_t bytes) -> void* {
    void* p = wsb + off;
    off = (off + bytes + 255) & ~(size_t)255;
    return p;
  };
  unsigned short* xgB   = (unsigned short*)carve((size_t)2 * NN * 64 * 2);   // 4 MiB
  unsigned short* t     = (unsigned short*)carve((size_t)2 * NN * 768 * 2);  // 48 MiB
  // carve 2P*16 B so the F alias (NN*768*2 = 24 MiB) always fits even though
  // sorted records are 8 B (uses only the first 2P*8 = 16 MiB)
  ushort4* sorted       = (ushort4*)carve((size_t)2 * P * 16);               // 32 MiB carve
  unsigned short* F = (unsigned short*)sorted;  // alias: sorted dead before fuse3
  unsigned short* w3T   = (unsigned short*)carve((size_t)2 * 768 * 64 * 2);
  unsigned short* fusT  = (unsigned short*)carve((size_t)768 * 2304 * 2);
  unsigned short* wB    = (unsigned short*)carve((size_t)1572864 * 2);       // pw4B|aw4B|semwB
  unsigned short* BTcat = (unsigned short*)carve((size_t)768 * 2048 * 2);
  unsigned short* w2T   = (unsigned short*)carve((size_t)2 * 4096 * 2);
  float* bias_tot = (float*)carve((size_t)768 * 4);
  unsigned* Gp2 = (unsigned*)carve((size_t)2 * 160 * 4);
  float* Mq2 = (float*)carve((size_t)32 * 4);
  unsigned* bcnt  = (unsigned*)carve((size_t)2 * NBUK * 4);
  unsigned* boffs = (unsigned*)carve((size_t)2 * (NBUK + 1) * 4);
  unsigned* bcur  = (unsigned*)carve((size_t)2 * NBUK * 4);
  // semB carved LAST so a too-small workspace only disables the bf16-sem path
  unsigned short* semB = (unsigned short*)carve((size_t)NN * 512 * 2);       // 16 MiB
  bool sem_bf = (off <= ws_size);

  // one mega-launch for all independent preprocessing (7 tasks)
  prep_misc<<<PM_TOT, 256, 0, stream>>>(
      bcnt,
      pw3, aw3, w3T,
      fusw, fusT,
      pw4, aw4, semw, wB,
      x_sem, semB, sem_bf ? 1 : 0,
      pw1, pb1, pg1, pbe1, aw1, ab1, ag1, abe1, pw2, aw2,
      Gp2, Mq2, w2T,
      fusb, pb4, ab4, semb, bias_tot);

  // fold GEMMs (96 blocks) + bucket histogram (128 blocks), one launch
  fold_hist<<<224, 256, 0, stream>>>(fusT, wB, BTcat, pos_idx, aff_idx, P, bcnt);

  scan_bucket<<<2, 1024, 0, stream>>>(bcnt, boffs, bcur);
  bucket_scatter<<<dim3(256, 2), 256, 0, stream>>>(x_pos, x_aff, pos_idx, aff_idx,
                                                   P, bcur, sorted);
  bucket_mlp_max<<<dim3(NBUK, 2), 256, 0, stream>>>(sorted, boffs,
                                                    (const __half2*)Gp2, Mq2,
                                                    w2T, pb2, ab2, xgB, P);

  gemm_w3_ln<<<dim3(NN / 32, 2), 256, 0, stream>>>(xgB, w3T, pb3, ab3,
                                                   pg2, pbe2, ag2, abe2, t);

  if (sem_bf)
    gemm_fuse3_v5<1><<<768, 256, 0, stream>>>(t, t + (size_t)NN * 768, semB, x_sem,
                                              BTcat, bias_tot, F);
  else
    gemm_fuse3_v5<0><<<768, 256, 0, stream>>>(t, t + (size_t)NN * 768, nullptr, x_sem,
                                              BTcat, bias_tot, F);
  ln_relu_768_f32<<<NN, 256, 0, stream>>>(F, fusg, fusbe, (float*)d_out);
}